// Round 1
// baseline (1962.154 us; speedup 1.0000x reference)
//
#include <hip/hip_runtime.h>
#include <math.h>

#define NV 8192        // N (nodes)
#define KD 256         // IN_DIM
#define DD 64          // OUT_DIM
#define ALPHA 0.2f
#define TI 64          // rows per block tile
#define CJ 128         // j-chunk
#define SW 132         // padded w_lds row stride (floats)
#define BLK 512

// ws layout (float offsets)
#define OFF_WH   0
#define OFF_F1   (NV * DD)            // 524288
#define OFF_F2   (OFF_F1 + NV)
#define OFF_MAX  (OFF_F2 + NV)
#define OFF_PACC (OFF_MAX + 128)      // 540800, 16B-aligned

// ---------------- kernel 1: Wh = h@W, f1 = Wh@a1, f2 = Wh@a2 ----------------
__global__ __launch_bounds__(256) void gat_pre(
    const float* __restrict__ h, const float* __restrict__ W,
    const float* __restrict__ a, float* __restrict__ Wh,
    float* __restrict__ f1, float* __restrict__ f2) {
  __shared__ float hrow[4][KD];
  const int wv = threadIdx.x >> 6, lane = threadIdx.x & 63;
  const long long i = (long long)blockIdx.x * 4 + wv;
  *(float4*)&hrow[wv][lane * 4] = *(const float4*)&h[i * KD + lane * 4];
  __syncthreads();
  float wh = 0.f;
#pragma unroll 8
  for (int c = 0; c < KD; ++c) wh += hrow[wv][c] * W[c * DD + lane];
  float p1 = wh * a[lane];
  float p2 = wh * a[DD + lane];
#pragma unroll
  for (int off = 32; off > 0; off >>= 1) {
    p1 += __shfl_down(p1, off);
    p2 += __shfl_down(p2, off);
  }
  Wh[i * DD + lane] = wh;
  if (lane == 0) { f1[i] = p1; f2[i] = p2; }
}

// ---------------- kernel 2: global max of f2 ----------------
__global__ __launch_bounds__(256) void gat_max(const float* __restrict__ f2,
                                               float* __restrict__ f2m) {
  __shared__ float red[4];
  const int tid = threadIdx.x;
  float m = -1e30f;
  for (int j = tid; j < NV; j += 256) m = fmaxf(m, f2[j]);
#pragma unroll
  for (int off = 32; off > 0; off >>= 1) m = fmaxf(m, __shfl_down(m, off));
  if ((tid & 63) == 0) red[tid >> 6] = m;
  __syncthreads();
  if (tid == 0) f2m[0] = fmaxf(fmaxf(red[0], red[1]), fmaxf(red[2], red[3]));
}

// ---------------- kernel 3: fused masked-softmax attention @ Wh ----------------
__global__ __launch_bounds__(BLK, 4) void gat_main(
    const int* __restrict__ A, const float* __restrict__ Wh,
    const float* __restrict__ f1, const float* __restrict__ f2,
    const float* __restrict__ f2max, float* __restrict__ pacc,
    float* __restrict__ pl, int S) {
  __shared__ float smem[TI * SW + CJ * DD];  // 16640 floats = 65 KB
  __shared__ float f1_lds[TI], M_lds[TI];
  float* w_lds = smem;              // [r][SW], chunk-local j
  float* wh_lds = smem + TI * SW;   // [j][DD]

  const int tid = threadIdx.x;
  const int nti = NV / TI;                 // 128
  const int tile = blockIdx.x % nti;
  const int s = blockIdx.x / nti;
  const int i0 = tile * TI;
  const int jrange = NV / S;
  const int j0 = s * jrange;

  if (tid < TI) {
    float v = f1[i0 + tid];
    f1_lds[tid] = v;
    float x = v + f2max[0];
    M_lds[tid] = x > 0.f ? x : ALPHA * x;  // guaranteed upper bound of row max
  }

  // stage-1 mapping (w compute): 32 lanes * 4 j each, 16 row-groups
  const int c4 = (tid & 31) * 4;
  const int rb = tid >> 5;        // 0..15
  // stage-2 mapping: 4 j-quarters x (16 k-groups x 8 row-groups)
  const int jq = tid >> 7;        // 0..3
  const int tq = tid & 127;
  const int k4 = (tq & 15) * 4;
  const int g = tq >> 4;          // 0..7
  const int jrot = 4 * (g & 3);   // bank-conflict-avoiding j rotation
  // l-reduction mapping: 8 threads per row
  const int lr = tid >> 3;        // 0..63
  const int lc = (tid & 7) * 16;

  float acc[8][4];
#pragma unroll
  for (int r = 0; r < 8; ++r)
#pragma unroll
    for (int c = 0; c < 4; ++c) acc[r][c] = 0.f;
  float lsum = 0.f;

  const int nch = jrange / CJ;
  for (int ch = 0; ch < nch; ++ch) {
    const int jb = j0 + ch * CJ;
    __syncthreads();  // previous iteration's readers done (and f1_lds ready)

    // ---- stage 1: compute w tile into LDS ----
    const float4 f2v = *(const float4*)(f2 + jb + c4);
#pragma unroll
    for (int p = 0; p < 4; ++p) {
      const int r = rb + 16 * p;
      const int4 a4 = *(const int4*)(A + (long long)(i0 + r) * NV + jb + c4);
      const float f1r = f1_lds[r];
      const float Mr = M_lds[r];
      float4 wv;
      { float x = f1r + f2v.x; x = x > 0.f ? x : ALPHA * x; wv.x = (a4.x > 0) ? __expf(x - Mr) : 0.f; }
      { float x = f1r + f2v.y; x = x > 0.f ? x : ALPHA * x; wv.y = (a4.y > 0) ? __expf(x - Mr) : 0.f; }
      { float x = f1r + f2v.z; x = x > 0.f ? x : ALPHA * x; wv.z = (a4.z > 0) ? __expf(x - Mr) : 0.f; }
      { float x = f1r + f2v.w; x = x > 0.f ? x : ALPHA * x; wv.w = (a4.w > 0) ? __expf(x - Mr) : 0.f; }
      *(float4*)(w_lds + r * SW + c4) = wv;
    }
    // ---- stage Wh chunk into LDS ----
#pragma unroll
    for (int q = 0; q < 4; ++q) {
      const int idx = (tid + q * BLK) * 4;
      *(float4*)(wh_lds + idx) = *(const float4*)(Wh + (long long)jb * DD + idx);
    }
    __syncthreads();

    // ---- l partial (row sums of w) ----
    {
      const float* wr = w_lds + lr * SW + lc;
      float s8 = 0.f;
#pragma unroll
      for (int q = 0; q < 16; ++q) s8 += wr[q];
      s8 += __shfl_down(s8, 4, 8);
      s8 += __shfl_down(s8, 2, 8);
      s8 += __shfl_down(s8, 1, 8);
      if ((tid & 7) == 0) lsum += s8;
    }

    // ---- stage 2: acc += w * Wh over this quarter's j ----
#pragma unroll
    for (int js = 0; js < 32; js += 4) {
      const int j = jq * 32 + ((js + jrot) & 31);
      const float4 wh0 = *(const float4*)(wh_lds + (j + 0) * DD + k4);
      const float4 wh1 = *(const float4*)(wh_lds + (j + 1) * DD + k4);
      const float4 wh2 = *(const float4*)(wh_lds + (j + 2) * DD + k4);
      const float4 wh3 = *(const float4*)(wh_lds + (j + 3) * DD + k4);
#pragma unroll
      for (int rr = 0; rr < 8; ++rr) {
        const int r = g * 8 + rr;
        const float4 wf = *(const float4*)(w_lds + r * SW + j);
        acc[rr][0] += wf.x * wh0.x + wf.y * wh1.x + wf.z * wh2.x + wf.w * wh3.x;
        acc[rr][1] += wf.x * wh0.y + wf.y * wh1.y + wf.z * wh2.y + wf.w * wh3.y;
        acc[rr][2] += wf.x * wh0.z + wf.y * wh1.z + wf.z * wh2.z + wf.w * wh3.z;
        acc[rr][3] += wf.x * wh0.w + wf.y * wh1.w + wf.z * wh2.w + wf.w * wh3.w;
      }
    }
  }

  if ((tid & 7) == 0) pl[(long long)s * NV + i0 + lr] = lsum;

  // ---- cross-quarter reduction through LDS (reuse smem) ----
  __syncthreads();
  float* red = smem;  // [jq][TI*DD] = 4*4096 floats <= 16640
#pragma unroll
  for (int rr = 0; rr < 8; ++rr) {
    const int r = g * 8 + rr;
    float4 v = make_float4(acc[rr][0], acc[rr][1], acc[rr][2], acc[rr][3]);
    *(float4*)(red + jq * (TI * DD) + r * DD + k4) = v;
  }
  __syncthreads();
  const long long obase = ((long long)s * NV + i0) * DD;
#pragma unroll
  for (int e = 0; e < 8; e += 4) {
    const int idx = tid * 8 + e;
    const float4 v0 = *(const float4*)(red + 0 * (TI * DD) + idx);
    const float4 v1 = *(const float4*)(red + 1 * (TI * DD) + idx);
    const float4 v2 = *(const float4*)(red + 2 * (TI * DD) + idx);
    const float4 v3 = *(const float4*)(red + 3 * (TI * DD) + idx);
    float4 o;
    o.x = v0.x + v1.x + v2.x + v3.x;
    o.y = v0.y + v1.y + v2.y + v3.y;
    o.z = v0.z + v1.z + v2.z + v3.z;
    o.w = v0.w + v1.w + v2.w + v3.w;
    *(float4*)(pacc + obase + idx) = o;
  }
}

// ---------------- kernel 4: combine j-splits, normalize, ELU ----------------
__global__ __launch_bounds__(256) void gat_fin(const float* __restrict__ pacc,
                                               const float* __restrict__ pl,
                                               float* __restrict__ out, int S) {
  const int idx = blockIdx.x * 256 + threadIdx.x;
  const int i = idx >> 6;
  float sum = 0.f, l = 0.f;
  for (int q = 0; q < S; ++q) sum += pacc[(long long)q * (NV * DD) + idx];
  for (int q = 0; q < S; ++q) l += pl[q * NV + i];
  const float v = sum / l;
  out[idx] = v > 0.f ? v : expm1f(v);  // ELU, alpha=1
}

extern "C" void kernel_launch(void* const* d_in, const int* in_sizes, int n_in,
                              void* d_out, int out_size, void* d_ws, size_t ws_size,
                              hipStream_t stream) {
  const float* h = (const float*)d_in[0];
  const int* A = (const int*)d_in[1];
  const float* W = (const float*)d_in[2];
  const float* a = (const float*)d_in[3];
  float* out = (float*)d_out;
  float* ws = (float*)d_ws;

  float* Wh = ws + OFF_WH;
  float* f1 = ws + OFF_F1;
  float* f2 = ws + OFF_F2;
  float* f2m = ws + OFF_MAX;
  float* pacc = ws + OFF_PACC;

  // pick largest j-split S that fits the workspace (deterministic per session)
  int S = 4;
  while (S > 1 &&
         (size_t)(OFF_PACC + (size_t)S * (NV * DD + NV)) * sizeof(float) > ws_size)
    S >>= 1;
  float* pl = pacc + (size_t)S * NV * DD;

  gat_pre<<<NV / 4, 256, 0, stream>>>(h, W, a, Wh, f1, f2);
  gat_max<<<1, 256, 0, stream>>>(f2, f2m);
  gat_main<<<(NV / TI) * S, BLK, 0, stream>>>(A, Wh, f1, f2, f2m, pacc, pl, S);
  gat_fin<<<NV * DD / 256, 256, 0, stream>>>(pacc, pl, out, S);
}

// Round 2
// 1046.097 us; speedup vs baseline: 1.8757x; 1.8757x over previous
//
#include <hip/hip_runtime.h>
#include <math.h>

#define NV 8192        // N (nodes)
#define KD 256         // IN_DIM
#define DD 64          // OUT_DIM
#define ALPHA 0.2f
#define TI 64          // rows per block tile
#define CJ 128         // j-chunk
#define SW 132         // padded w_lds row stride (floats)
#define BLK 512

// ws layout (float offsets)
#define OFF_WH   0
#define OFF_F1   (NV * DD)            // 524288
#define OFF_F2   (OFF_F1 + NV)
#define OFF_MAX  (OFF_F2 + NV)
#define OFF_PACC (OFF_MAX + 128)      // 540800, 16B-aligned

// ---------------- kernel 1: Wh = h@W, f1 = Wh@a1, f2 = Wh@a2 ----------------
__global__ __launch_bounds__(256) void gat_pre(
    const float* __restrict__ h, const float* __restrict__ W,
    const float* __restrict__ a, float* __restrict__ Wh,
    float* __restrict__ f1, float* __restrict__ f2) {
  __shared__ float hrow[4][KD];
  const int wv = threadIdx.x >> 6, lane = threadIdx.x & 63;
  const long long i = (long long)blockIdx.x * 4 + wv;
  *(float4*)&hrow[wv][lane * 4] = *(const float4*)&h[i * KD + lane * 4];
  __syncthreads();
  float wh = 0.f;
#pragma unroll 8
  for (int c = 0; c < KD; ++c) wh += hrow[wv][c] * W[c * DD + lane];
  float p1 = wh * a[lane];
  float p2 = wh * a[DD + lane];
#pragma unroll
  for (int off = 32; off > 0; off >>= 1) {
    p1 += __shfl_down(p1, off);
    p2 += __shfl_down(p2, off);
  }
  Wh[i * DD + lane] = wh;
  if (lane == 0) { f1[i] = p1; f2[i] = p2; }
}

// ---------------- kernel 2: global max of f2 ----------------
__global__ __launch_bounds__(256) void gat_max(const float* __restrict__ f2,
                                               float* __restrict__ f2m) {
  __shared__ float red[4];
  const int tid = threadIdx.x;
  float m = -1e30f;
  for (int j = tid; j < NV; j += 256) m = fmaxf(m, f2[j]);
#pragma unroll
  for (int off = 32; off > 0; off >>= 1) m = fmaxf(m, __shfl_down(m, off));
  if ((tid & 63) == 0) red[tid >> 6] = m;
  __syncthreads();
  if (tid == 0) f2m[0] = fmaxf(fmaxf(red[0], red[1]), fmaxf(red[2], red[3]));
}

// ---------------- kernel 3: fused masked-softmax attention @ Wh ----------------
// __launch_bounds__(BLK) with NO min-waves arg: R1's (BLK,4) clamped VGPRs to 64
// and spilled acc[8][4] -> 3.4 GB scratch writes, VALUBusy 5.7%. Occupancy is
// LDS-limited (67 KB -> 2 blocks/CU) regardless, so the clamp bought nothing.
__global__ __launch_bounds__(BLK) void gat_main(
    const int* __restrict__ A, const float* __restrict__ Wh,
    const float* __restrict__ f1, const float* __restrict__ f2,
    const float* __restrict__ f2max, float* __restrict__ pacc,
    float* __restrict__ pl, int S) {
  __shared__ float smem[TI * SW + CJ * DD];  // 16640 floats = 65 KB
  __shared__ float f1_lds[TI], M_lds[TI];
  float* w_lds = smem;              // [r][SW], chunk-local j
  float* wh_lds = smem + TI * SW;   // [j][DD]

  const int tid = threadIdx.x;
  const int nti = NV / TI;                 // 128
  const int tile = blockIdx.x % nti;
  const int s = blockIdx.x / nti;
  const int i0 = tile * TI;
  const int jrange = NV / S;
  const int j0 = s * jrange;

  if (tid < TI) {
    float v = f1[i0 + tid];
    f1_lds[tid] = v;
    float x = v + f2max[0];
    M_lds[tid] = x > 0.f ? x : ALPHA * x;  // guaranteed upper bound of row max
  }

  // stage-1 mapping (w compute): 32 lanes * 4 j each, 16 row-groups
  const int c4 = (tid & 31) * 4;
  const int rb = tid >> 5;        // 0..15
  // stage-2 mapping: 4 j-quarters x (16 k-groups x 8 row-groups)
  const int jq = tid >> 7;        // 0..3
  const int tq = tid & 127;
  const int k4 = (tq & 15) * 4;
  const int g = tq >> 4;          // 0..7
  const int jrot = 4 * (g & 3);   // bank-conflict-avoiding j rotation
  // l-reduction mapping: 8 threads per row
  const int lr = tid >> 3;        // 0..63
  const int lc = (tid & 7) * 16;

  float acc[8][4];
#pragma unroll
  for (int r = 0; r < 8; ++r)
#pragma unroll
    for (int c = 0; c < 4; ++c) acc[r][c] = 0.f;
  float lsum = 0.f;

  const int nch = jrange / CJ;
  for (int ch = 0; ch < nch; ++ch) {
    const int jb = j0 + ch * CJ;
    __syncthreads();  // previous iteration's readers done (and f1_lds ready)

    // ---- stage 1: compute w tile into LDS ----
    const float4 f2v = *(const float4*)(f2 + jb + c4);
#pragma unroll
    for (int p = 0; p < 4; ++p) {
      const int r = rb + 16 * p;
      const int4 a4 = *(const int4*)(A + (long long)(i0 + r) * NV + jb + c4);
      const float f1r = f1_lds[r];
      const float Mr = M_lds[r];
      float4 wv;
      { float x = f1r + f2v.x; x = x > 0.f ? x : ALPHA * x; wv.x = (a4.x > 0) ? __expf(x - Mr) : 0.f; }
      { float x = f1r + f2v.y; x = x > 0.f ? x : ALPHA * x; wv.y = (a4.y > 0) ? __expf(x - Mr) : 0.f; }
      { float x = f1r + f2v.z; x = x > 0.f ? x : ALPHA * x; wv.z = (a4.z > 0) ? __expf(x - Mr) : 0.f; }
      { float x = f1r + f2v.w; x = x > 0.f ? x : ALPHA * x; wv.w = (a4.w > 0) ? __expf(x - Mr) : 0.f; }
      *(float4*)(w_lds + r * SW + c4) = wv;
    }
    // ---- stage Wh chunk into LDS ----
#pragma unroll
    for (int q = 0; q < 4; ++q) {
      const int idx = (tid + q * BLK) * 4;
      *(float4*)(wh_lds + idx) = *(const float4*)(Wh + (long long)jb * DD + idx);
    }
    __syncthreads();

    // ---- l partial (row sums of w) ----
    {
      const float* wr = w_lds + lr * SW + lc;
      float s8 = 0.f;
#pragma unroll
      for (int q = 0; q < 16; ++q) s8 += wr[q];
      s8 += __shfl_down(s8, 4, 8);
      s8 += __shfl_down(s8, 2, 8);
      s8 += __shfl_down(s8, 1, 8);
      if ((tid & 7) == 0) lsum += s8;
    }

    // ---- stage 2: acc += w * Wh over this quarter's j ----
#pragma unroll
    for (int js = 0; js < 32; js += 4) {
      const int j = jq * 32 + ((js + jrot) & 31);
      const float4 wh0 = *(const float4*)(wh_lds + (j + 0) * DD + k4);
      const float4 wh1 = *(const float4*)(wh_lds + (j + 1) * DD + k4);
      const float4 wh2 = *(const float4*)(wh_lds + (j + 2) * DD + k4);
      const float4 wh3 = *(const float4*)(wh_lds + (j + 3) * DD + k4);
#pragma unroll
      for (int rr = 0; rr < 8; ++rr) {
        const int r = g * 8 + rr;
        const float4 wf = *(const float4*)(w_lds + r * SW + j);
        acc[rr][0] += wf.x * wh0.x + wf.y * wh1.x + wf.z * wh2.x + wf.w * wh3.x;
        acc[rr][1] += wf.x * wh0.y + wf.y * wh1.y + wf.z * wh2.y + wf.w * wh3.y;
        acc[rr][2] += wf.x * wh0.z + wf.y * wh1.z + wf.z * wh2.z + wf.w * wh3.z;
        acc[rr][3] += wf.x * wh0.w + wf.y * wh1.w + wf.z * wh2.w + wf.w * wh3.w;
      }
    }
  }

  if ((tid & 7) == 0) pl[(long long)s * NV + i0 + lr] = lsum;

  // ---- cross-quarter reduction through LDS (reuse smem) ----
  __syncthreads();
  float* red = smem;  // [jq][TI*DD] = 4*4096 floats <= 16640
#pragma unroll
  for (int rr = 0; rr < 8; ++rr) {
    const int r = g * 8 + rr;
    float4 v = make_float4(acc[rr][0], acc[rr][1], acc[rr][2], acc[rr][3]);
    *(float4*)(red + jq * (TI * DD) + r * DD + k4) = v;
  }
  __syncthreads();
  const long long obase = ((long long)s * NV + i0) * DD;
#pragma unroll
  for (int e = 0; e < 8; e += 4) {
    const int idx = tid * 8 + e;
    const float4 v0 = *(const float4*)(red + 0 * (TI * DD) + idx);
    const float4 v1 = *(const float4*)(red + 1 * (TI * DD) + idx);
    const float4 v2 = *(const float4*)(red + 2 * (TI * DD) + idx);
    const float4 v3 = *(const float4*)(red + 3 * (TI * DD) + idx);
    float4 o;
    o.x = v0.x + v1.x + v2.x + v3.x;
    o.y = v0.y + v1.y + v2.y + v3.y;
    o.z = v0.z + v1.z + v2.z + v3.z;
    o.w = v0.w + v1.w + v2.w + v3.w;
    *(float4*)(pacc + obase + idx) = o;
  }
}

// ---------------- kernel 4: combine j-splits, normalize, ELU ----------------
__global__ __launch_bounds__(256) void gat_fin(const float* __restrict__ pacc,
                                               const float* __restrict__ pl,
                                               float* __restrict__ out, int S) {
  const int idx = blockIdx.x * 256 + threadIdx.x;
  const int i = idx >> 6;
  float sum = 0.f, l = 0.f;
  for (int q = 0; q < S; ++q) sum += pacc[(long long)q * (NV * DD) + idx];
  for (int q = 0; q < S; ++q) l += pl[q * NV + i];
  const float v = sum / l;
  out[idx] = v > 0.f ? v : expm1f(v);  // ELU, alpha=1
}

extern "C" void kernel_launch(void* const* d_in, const int* in_sizes, int n_in,
                              void* d_out, int out_size, void* d_ws, size_t ws_size,
                              hipStream_t stream) {
  const float* h = (const float*)d_in[0];
  const int* A = (const int*)d_in[1];
  const float* W = (const float*)d_in[2];
  const float* a = (const float*)d_in[3];
  float* out = (float*)d_out;
  float* ws = (float*)d_ws;

  float* Wh = ws + OFF_WH;
  float* f1 = ws + OFF_F1;
  float* f2 = ws + OFF_F2;
  float* f2m = ws + OFF_MAX;
  float* pacc = ws + OFF_PACC;

  // pick largest j-split S that fits the workspace (deterministic per session)
  int S = 4;
  while (S > 1 &&
         (size_t)(OFF_PACC + (size_t)S * (NV * DD + NV)) * sizeof(float) > ws_size)
    S >>= 1;
  float* pl = pacc + (size_t)S * NV * DD;

  gat_pre<<<NV / 4, 256, 0, stream>>>(h, W, a, Wh, f1, f2);
  gat_max<<<1, 256, 0, stream>>>(f2, f2m);
  gat_main<<<(NV / TI) * S, BLK, 0, stream>>>(A, Wh, f1, f2, f2m, pacc, pl, S);
  gat_fin<<<NV * DD / 256, 256, 0, stream>>>(pacc, pl, out, S);
}

// Round 3
// 396.830 us; speedup vs baseline: 4.9446x; 2.6361x over previous
//
#include <hip/hip_runtime.h>
#include <math.h>
#include <stdint.h>

#define NV 8192        // N (nodes)
#define KD 256         // IN_DIM
#define DD 64          // OUT_DIM
#define ALPHA 0.2f
#define TI 64          // rows per block tile
#define CJ 128         // j-chunk (16 chunks of 8 f16)
#define BLK 512

typedef _Float16 half8 __attribute__((ext_vector_type(8)));
typedef float floatx4 __attribute__((ext_vector_type(4)));

// ws layout (float offsets)
#define OFF_WHT  0                        // WhT f16 [DD][NV] = 262144 floats
#define OFF_F1   (DD * NV / 2)
#define OFF_F2   (OFF_F1 + NV)
#define OFF_PACC (OFF_F2 + NV)            // then pacc[S][NV][DD], pl[S][NV]

// ---------------- kernel 1: WhT(f16) = (h@W)^T, f1 = Wh@a1, f2 = Wh@a2 ----------------
__global__ __launch_bounds__(256) void gat_pre(
    const float* __restrict__ h, const float* __restrict__ W,
    const float* __restrict__ a, ushort* __restrict__ whT,
    float* __restrict__ f1, float* __restrict__ f2) {
  __shared__ float hrow[4][KD];
  __shared__ __align__(8) ushort tw[DD][4];  // transpose buffer [d][i']
  const int wv = threadIdx.x >> 6, lane = threadIdx.x & 63;
  const int i = blockIdx.x * 4 + wv;
  *(float4*)&hrow[wv][lane * 4] = *(const float4*)&h[(long long)i * KD + lane * 4];
  __syncthreads();
  float wh = 0.f;
#pragma unroll 8
  for (int c = 0; c < KD; ++c) wh += hrow[wv][c] * W[c * DD + lane];
  float p1 = wh * a[lane];
  float p2 = wh * a[DD + lane];
#pragma unroll
  for (int off = 32; off > 0; off >>= 1) {
    p1 += __shfl_down(p1, off);
    p2 += __shfl_down(p2, off);
  }
  if (lane == 0) { f1[i] = p1; f2[i] = p2; }
  union { _Float16 hf; ushort u; } cv;
  cv.hf = (_Float16)wh;
  tw[lane][wv] = cv.u;
  __syncthreads();
  if (threadIdx.x < DD) {  // write 4 i-values of row d: 8 B store
    *(uint2*)&whT[(long long)threadIdx.x * NV + blockIdx.x * 4] = *(uint2*)&tw[threadIdx.x][0];
  }
}

// ---------------- kernel 2: fused masked-softmax attention @ Wh (MFMA f16) ----------------
// LDS layout for both operands: [row 0..63][16 chunks of 16B], chunk col XOR-swizzled
// with (row&15) so frag reads (b128) and stage-1 writes are >=2-way-free (free per m136).
// No __launch_bounds__ min-waves arg (R1 lesson); acc is only 8 fp32/thread (R2 spill fix).
__global__ __launch_bounds__(BLK) void gat_main(
    const int* __restrict__ A, const ushort* __restrict__ whT,
    const float* __restrict__ f1, const float* __restrict__ f2,
    float* __restrict__ pacc, float* __restrict__ pl, int S) {
  __shared__ __align__(16) ushort w_lds[TI * CJ];  // 16 KB, A-operand (rows i)
  __shared__ __align__(16) ushort b_lds[TI * CJ];  // 16 KB, B-operand (rows d)
  __shared__ float f1_lds[TI], M_lds[TI], redf[8];

  const int tid = threadIdx.x;
  const int wave = tid >> 6, lane = tid & 63;
  const int tile = blockIdx.x & 127;  // NV/TI = 128
  const int s = blockIdx.x >> 7;
  const int i0 = tile * TI;
  const int jrange = NV / S;
  const int j0 = s * jrange;

  // block-redundant global max of f2 (replaces the old gat_max kernel)
  float m = -1e30f;
#pragma unroll
  for (int q = 0; q < 16; ++q) m = fmaxf(m, f2[tid + q * BLK]);
#pragma unroll
  for (int off = 32; off > 0; off >>= 1) m = fmaxf(m, __shfl_down(m, off));
  if (lane == 0) redf[wave] = m;
  __syncthreads();
  if (tid < TI) {
    float mm = redf[0];
#pragma unroll
    for (int k = 1; k < 8; ++k) mm = fmaxf(mm, redf[k]);
    float v = f1[i0 + tid];
    f1_lds[tid] = v;
    float x = v + mm;                      // M_i = lrelu(f1_i + max f2) >= all row
    M_lds[tid] = x > 0.f ? x : ALPHA * x;  // logits (lrelu monotone) -> w <= 1, f16-safe
  }

  // stage-1 mapping: thread covers cols c4..c4+3 of rows rb+16p
  const int c4 = (tid & 31) * 4;
  const int k8w = (tid & 31) >> 1;   // 16B-chunk col for writes
  const int sub = (tid & 1) * 8;     // byte offset within chunk
  const int rb = tid >> 5;           // 0..15
  // MFMA mapping: wave -> m-tile (wave>>1), two n-tiles
  const int mt = wave >> 1;
  const int nt0 = (wave & 1) * 2;
  const int m_ = lane & 15, quad = lane >> 4;

  floatx4 acc0 = {0.f, 0.f, 0.f, 0.f}, acc1 = {0.f, 0.f, 0.f, 0.f};
  float lp[4] = {0.f, 0.f, 0.f, 0.f};

  const int nch = jrange / CJ;
  for (int ch = 0; ch < nch; ++ch) {
    const int jb = j0 + ch * CJ;
    __syncthreads();  // previous chunk's readers done (also covers M_lds init)

    // ---- stage B chunk: gather WhT with XOR swizzle into linear LDS ----
#pragma unroll
    for (int u = 0; u < 2; ++u) {
      const int idx = tid + u * BLK;  // 0..1023 chunk slots
      const int n = idx >> 4, c = idx & 15;
      const uint4 t = *(const uint4*)(whT + (long long)n * NV + jb + 8 * (c ^ (n & 15)));
      *(uint4*)&b_lds[idx * 8] = t;
    }

    // ---- stage 1: w = A ? exp(lrelu(f1+f2) - M) : 0, as f16 into w_lds ----
    const float4 f2v = *(const float4*)(f2 + jb + c4);
#pragma unroll
    for (int p = 0; p < 4; ++p) {
      const int r = rb + 16 * p;
      const int4 a4 = *(const int4*)(A + (long long)(i0 + r) * NV + jb + c4);
      const float f1r = f1_lds[r], Mr = M_lds[r];
      float w0, w1, w2, w3;
      { float x = f1r + f2v.x; x = x > 0.f ? x : ALPHA * x; w0 = (a4.x > 0) ? __expf(x - Mr) : 0.f; }
      { float x = f1r + f2v.y; x = x > 0.f ? x : ALPHA * x; w1 = (a4.y > 0) ? __expf(x - Mr) : 0.f; }
      { float x = f1r + f2v.z; x = x > 0.f ? x : ALPHA * x; w2 = (a4.z > 0) ? __expf(x - Mr) : 0.f; }
      { float x = f1r + f2v.w; x = x > 0.f ? x : ALPHA * x; w3 = (a4.w > 0) ? __expf(x - Mr) : 0.f; }
      union { _Float16 hf[4]; uint2 u2; } pk;
      pk.hf[0] = (_Float16)w0; pk.hf[1] = (_Float16)w1;
      pk.hf[2] = (_Float16)w2; pk.hf[3] = (_Float16)w3;
      // sum the f16-rounded values so softmax stays exactly normalized
      lp[p] += (float)pk.hf[0] + (float)pk.hf[1] + (float)pk.hf[2] + (float)pk.hf[3];
      *(uint2*)((char*)w_lds + (r * 16 + (k8w ^ (r & 15))) * 16 + sub) = pk.u2;
    }
    __syncthreads();

    // ---- stage 2: MFMA, 2 C-tiles per wave, 4 k-steps ----
#pragma unroll
    for (int ks = 0; ks < 4; ++ks) {
      const int cc = 4 * ks + quad;
      const half8 af = *(const half8*)((const char*)w_lds + (((16 * mt + m_) * 16) + (cc ^ m_)) * 16);
      const half8 b0 = *(const half8*)((const char*)b_lds + (((16 * nt0 + m_) * 16) + (cc ^ m_)) * 16);
      const half8 b1 = *(const half8*)((const char*)b_lds + (((16 * (nt0 + 1) + m_) * 16) + (cc ^ m_)) * 16);
      acc0 = __builtin_amdgcn_mfma_f32_16x16x32_f16(af, b0, acc0, 0, 0, 0);
      acc1 = __builtin_amdgcn_mfma_f32_16x16x32_f16(af, b1, acc1, 0, 0, 0);
    }
  }

  // ---- pl: reduce thread-local row-sum partials across each 32-lane group ----
#pragma unroll
  for (int p = 0; p < 4; ++p) {
    float v = lp[p];
    v += __shfl_down(v, 16, 32);
    v += __shfl_down(v, 8, 32);
    v += __shfl_down(v, 4, 32);
    v += __shfl_down(v, 2, 32);
    v += __shfl_down(v, 1, 32);
    if ((tid & 31) == 0) pl[(long long)s * NV + i0 + rb + 16 * p] = v;
  }

  // ---- epilogue: C/D layout row=quad*4+reg, col=lane&15 (verified m89/m91) ----
#pragma unroll
  for (int reg = 0; reg < 4; ++reg) {
    const int i = i0 + 16 * mt + quad * 4 + reg;
    const long long base = ((long long)s * NV + i) * DD + m_;
    pacc[base + 16 * nt0] = acc0[reg];
    pacc[base + 16 * (nt0 + 1)] = acc1[reg];
  }
}

// ---------------- kernel 3: combine j-splits, normalize, ELU ----------------
__global__ __launch_bounds__(256) void gat_fin(const float* __restrict__ pacc,
                                               const float* __restrict__ pl,
                                               float* __restrict__ out, int S) {
  const int idx = blockIdx.x * 256 + threadIdx.x;
  const int i = idx >> 6;
  float sum = 0.f, l = 0.f;
  for (int q = 0; q < S; ++q) sum += pacc[(long long)q * (NV * DD) + idx];
  for (int q = 0; q < S; ++q) l += pl[q * NV + i];
  const float v = sum / l;
  out[idx] = v > 0.f ? v : expm1f(v);  // ELU, alpha=1
}

extern "C" void kernel_launch(void* const* d_in, const int* in_sizes, int n_in,
                              void* d_out, int out_size, void* d_ws, size_t ws_size,
                              hipStream_t stream) {
  const float* h = (const float*)d_in[0];
  const int* A = (const int*)d_in[1];
  const float* W = (const float*)d_in[2];
  const float* a = (const float*)d_in[3];
  float* out = (float*)d_out;
  float* ws = (float*)d_ws;

  ushort* whT = (ushort*)(ws + OFF_WHT);
  float* f1 = ws + OFF_F1;
  float* f2 = ws + OFF_F2;
  float* pacc = ws + OFF_PACC;

  // pick largest j-split S that fits the workspace
  int S = 4;
  while (S > 1 &&
         (size_t)(OFF_PACC + (size_t)S * (NV * DD + NV)) * sizeof(float) > ws_size)
    S >>= 1;
  float* pl = pacc + (size_t)S * NV * DD;

  gat_pre<<<NV / 4, 256, 0, stream>>>(h, W, a, whT, f1, f2);
  gat_main<<<(NV / TI) * S, BLK, 0, stream>>>(A, whT, f1, f2, pacc, pl, S);
  gat_fin<<<NV * DD / 256, 256, 0, stream>>>(pacc, pl, out, S);
}